// Round 9
// baseline (175.434 us; speedup 1.0000x reference)
//
#include <hip/hip_runtime.h>
#include <math.h>

#define F 256
#define E 256
#define S 32
#define CH 4
#define NB 8      // nodes per fused block -> grid 1250, ~4.9 blocks/CU
#define TLP 260   // tile row stride in uints: 1040 B, 16B-aligned rows

typedef __attribute__((ext_vector_type(8))) short short8;
typedef __attribute__((ext_vector_type(4))) float f32x4;

__device__ __forceinline__ ushort f2bf(float x) {
    uint u = __float_as_uint(x);
    return (ushort)((u + 0x7fffu + ((u >> 16) & 1u)) >> 16);
}
__device__ __forceinline__ float bf2f(ushort h) {
    return __uint_as_float(((uint)h) << 16);
}
__device__ __forceinline__ uint4 pack8(const ushort* h) {
    uint4 r;
    r.x = (uint)h[0] | ((uint)h[1] << 16); r.y = (uint)h[2] | ((uint)h[3] << 16);
    r.z = (uint)h[4] | ((uint)h[5] << 16); r.w = (uint)h[6] | ((uint)h[7] << 16);
    return r;
}
__device__ __forceinline__ void split8(const float* x, short8& h, short8& l) {
    ushort hh[8], ll[8];
#pragma unroll
    for (int i = 0; i < 8; ++i) { hh[i] = f2bf(x[i]); ll[i] = f2bf(x[i] - bf2f(hh[i])); }
    uint4 ph = pack8(hh), pl = pack8(ll);
    h = *reinterpret_cast<short8*>(&ph);
    l = *reinterpret_cast<short8*>(&pl);
}
__device__ __forceinline__ short8 mk8(uint a, uint b, uint c, uint d) {
    uint4 p = make_uint4(a, b, c, d);
    return *reinterpret_cast<short8*>(&p);
}
__device__ __forceinline__ uint pkbf(float v) {
    const ushort h = f2bf(v);
    const ushort l = f2bf(v - bf2f(h));
    return (uint)h | ((uint)l << 16);
}

// ---------------------------------------------------------------------------
// prep (unchanged): blocks 0..3 -> MT[j][i] = Wk_j . Wq_i (bf16x3 MFMA from
// global), split hi/lo; blocks 4..19 -> WvT transpose/split; 20..23 -> c.
// ---------------------------------------------------------------------------
__global__ __launch_bounds__(512) void prep(const float* __restrict__ Wq,
                                            const float* __restrict__ bq,
                                            const float* __restrict__ Wk,
                                            const float* __restrict__ Wv,
                                            ushort* __restrict__ MTh,
                                            ushort* __restrict__ MTl,
                                            ushort* __restrict__ WvTh,
                                            ushort* __restrict__ WvTl,
                                            float* __restrict__ c) {
    const int blk = blockIdx.x, tid = threadIdx.x;
    const int lane = tid & 63, wave = tid >> 6;
    if (blk < 4) {
        const int wm = wave >> 2, wn = wave & 3;
        const int fr = lane & 15, fk = lane >> 4;
        const int j0 = blk * 64;
        f32x4 acc[2][4];
#pragma unroll
        for (int m = 0; m < 2; ++m)
#pragma unroll
            for (int n = 0; n < 4; ++n) acc[m][n] = (f32x4){0.f, 0.f, 0.f, 0.f};
        for (int k0 = 0; k0 < F; k0 += 32) {
            short8 ah[2], al[2];
#pragma unroll
            for (int m = 0; m < 2; ++m) {
                const float* p = &Wk[(size_t)(j0 + wm * 32 + m * 16 + fr) * F + k0 + fk * 8];
                float x[8];
                *reinterpret_cast<float4*>(&x[0]) = *reinterpret_cast<const float4*>(p);
                *reinterpret_cast<float4*>(&x[4]) = *reinterpret_cast<const float4*>(p + 4);
                split8(x, ah[m], al[m]);
            }
#pragma unroll
            for (int n = 0; n < 4; ++n) {
                const float* p = &Wq[(size_t)(wn * 64 + n * 16 + fr) * F + k0 + fk * 8];
                float x[8];
                *reinterpret_cast<float4*>(&x[0]) = *reinterpret_cast<const float4*>(p);
                *reinterpret_cast<float4*>(&x[4]) = *reinterpret_cast<const float4*>(p + 4);
                short8 bh, bl;
                split8(x, bh, bl);
#pragma unroll
                for (int m = 0; m < 2; ++m) {
                    acc[m][n] = __builtin_amdgcn_mfma_f32_16x16x32_bf16(ah[m], bh, acc[m][n], 0, 0, 0);
                    acc[m][n] = __builtin_amdgcn_mfma_f32_16x16x32_bf16(ah[m], bl, acc[m][n], 0, 0, 0);
                    acc[m][n] = __builtin_amdgcn_mfma_f32_16x16x32_bf16(al[m], bh, acc[m][n], 0, 0, 0);
                }
            }
        }
#pragma unroll
        for (int n = 0; n < 4; ++n) {
            const int i = wn * 64 + n * 16 + fr;
#pragma unroll
            for (int m = 0; m < 2; ++m)
#pragma unroll
                for (int r = 0; r < 4; ++r) {
                    const int j = j0 + wm * 32 + m * 16 + fk * 4 + r;
                    const float v = acc[m][n][r];
                    const ushort h = f2bf(v);
                    MTh[(size_t)j * F + i] = h;
                    MTl[(size_t)j * F + i] = f2bf(v - bf2f(h));
                }
        }
    } else if (blk < 20) {
        __shared__ float t[64][65];
        const int tb = blk - 4;
        const int jt = (tb & 3) * 64, kt = (tb >> 2) * 64;
        const int lk = tid >> 3, lj = (tid & 7) * 8;
        {
            const float* p = &Wv[(size_t)(kt + lk) * E + jt + lj];
            const float4 v0 = *reinterpret_cast<const float4*>(p);
            const float4 v1 = *reinterpret_cast<const float4*>(p + 4);
            t[lk][lj + 0] = v0.x; t[lk][lj + 1] = v0.y; t[lk][lj + 2] = v0.z; t[lk][lj + 3] = v0.w;
            t[lk][lj + 4] = v1.x; t[lk][lj + 5] = v1.y; t[lk][lj + 6] = v1.z; t[lk][lj + 7] = v1.w;
        }
        __syncthreads();
        const int oj = tid >> 3, ok = (tid & 7) * 8;
        ushort h[8], l[8];
#pragma unroll
        for (int u = 0; u < 8; ++u) {
            const float v = t[ok + u][oj];
            h[u] = f2bf(v); l[u] = f2bf(v - bf2f(h[u]));
        }
        *reinterpret_cast<uint4*>(&WvTh[(size_t)(jt + oj) * F + kt + ok]) = pack8(h);
        *reinterpret_cast<uint4*>(&WvTl[(size_t)(jt + oj) * F + kt + ok]) = pack8(l);
    } else {
        __shared__ float bqs[F];
        if (tid < F) bqs[tid] = bq[tid];
        __syncthreads();
        const float4 b4 = *reinterpret_cast<const float4*>(&bqs[lane * 4]);
#pragma unroll
        for (int i = 0; i < 8; ++i) {
            const int j = (blk - 20) * 64 + wave * 8 + i;
            const float4 k4 = *reinterpret_cast<const float4*>(&Wk[(size_t)j * F + lane * 4]);
            float p = k4.x * b4.x + k4.y * b4.y + k4.z * b4.z + k4.w * b4.w;
#pragma unroll
            for (int off = 32; off; off >>= 1) p += __shfl_xor(p, off);
            if (lane == 0) c[j] = p;
        }
    }
}

// ---------------------------------------------------------------------------
// attn helpers (proven online-softmax gather, R3)
// ---------------------------------------------------------------------------
__device__ __forceinline__ void ld_chunk(float4* d, int idxv, int s0,
                                         const float* __restrict__ t, int lane) {
#pragma unroll
    for (int j = 0; j < CH; ++j) {
        const int nid = __builtin_amdgcn_readlane(idxv, s0 + j);
        d[j] = *reinterpret_cast<const float4*>(&t[(size_t)nid * F + lane * 4]);
    }
}
__device__ __forceinline__ void proc_chunk(const float4* v, const float4 qv,
                                           float& m, float& l, float4& acc) {
#pragma unroll
    for (int j = 0; j < CH; ++j) {
        float p = v[j].x * qv.x + v[j].y * qv.y + v[j].z * qv.z + v[j].w * qv.w;
#pragma unroll
        for (int off = 32; off; off >>= 1) p += __shfl_xor(p, off);
        if (p <= m) {
            const float w = __expf(p - m);
            l += w;
            acc.x += w * v[j].x; acc.y += w * v[j].y;
            acc.z += w * v[j].z; acc.w += w * v[j].w;
        } else {
            const float cc = __expf(m - p);
            l = l * cc + 1.f;
            acc.x = acc.x * cc + v[j].x; acc.y = acc.y * cc + v[j].y;
            acc.z = acc.z * cc + v[j].z; acc.w = acc.w * cc + v[j].w;
            m = p;
        }
    }
}

// ---------------------------------------------------------------------------
// fused v4: one block = 8 nodes, 256 thr = 4 waves -> grid 1250, ~4.9
// blocks/CU, ~19.5 waves/CU (the standalone gather's 61%-occ operating
// point). ~5 independent blocks per CU are at different phases, so the
// barrier convoy of one block is covered by the gather waves of others.
// Phase B: q~[8x256] = gather @ MT + c (M-rows 8..15 of the MFMA tile are
//          don't-care; each wave owns 4 N-fragments) -> LDS tile
// Phase A: online-softmax gather, 2 nodes/wave (standalone wall config)
// Phase D: out = m @ WvT + bv (A unpacked from tile, rows mirrored)
// ---------------------------------------------------------------------------
__global__ __launch_bounds__(256) void fused(const int* __restrict__ nodes,
                                             const int* __restrict__ neigh,
                                             const float* __restrict__ id2feat,
                                             const ushort* __restrict__ MTh,
                                             const ushort* __restrict__ MTl,
                                             const ushort* __restrict__ WvTh,
                                             const ushort* __restrict__ WvTl,
                                             const float* __restrict__ cb,
                                             const float* __restrict__ bv,
                                             float* __restrict__ out,
                                             int B) {
    __shared__ uint tile[NB][TLP];   // q~ f32 bits -> m packed (hi|lo) bf16

    const int tid = threadIdx.x;
    const int lane = tid & 63, wave = tid >> 6;   // wave 0..3
    const int fr = lane & 15, fk = lane >> 4;
    const int row0 = blockIdx.x * NB;

    // ---------------- phase B ----------------
    // A-operand rows: fr&7 (rows 8..15 duplicate 0..7; their C rows discarded)
    const int gr = row0 + (fr & 7);
    const int arow = nodes[gr < B ? gr : B - 1];

    f32x4 acc[4];
#pragma unroll
    for (int n = 0; n < 4; ++n) acc[n] = (f32x4){0.f, 0.f, 0.f, 0.f};

    for (int k0 = 0; k0 < F; k0 += 32) {
        const float* p = id2feat + (size_t)arow * F + k0 + fk * 8;
        float x[8];
        *reinterpret_cast<float4*>(&x[0]) = *reinterpret_cast<const float4*>(p);
        *reinterpret_cast<float4*>(&x[4]) = *reinterpret_cast<const float4*>(p + 4);
        short8 ah, al;
        split8(x, ah, al);
#pragma unroll
        for (int n = 0; n < 4; ++n) {
            const size_t boff = (size_t)((wave * 4 + n) * 16 + fr) * F + k0 + fk * 8;
            const short8 bh = *reinterpret_cast<const short8*>(&MTh[boff]);
            const short8 bl = *reinterpret_cast<const short8*>(&MTl[boff]);
            acc[n] = __builtin_amdgcn_mfma_f32_16x16x32_bf16(ah, bh, acc[n], 0, 0, 0);
            acc[n] = __builtin_amdgcn_mfma_f32_16x16x32_bf16(ah, bl, acc[n], 0, 0, 0);
            acc[n] = __builtin_amdgcn_mfma_f32_16x16x32_bf16(al, bh, acc[n], 0, 0, 0);
        }
    }
    if (fk < 2) {    // C rows 0..7 valid (row = fk*4 + r)
#pragma unroll
        for (int n = 0; n < 4; ++n) {
            const int col = (wave * 4 + n) * 16 + fr;
            const float cc = cb[col];
#pragma unroll
            for (int r = 0; r < 4; ++r)
                tile[fk * 4 + r][col] = __float_as_uint(acc[n][r] + cc);
        }
    }
    __syncthreads();

    // ---------------- phase attn (2 nodes per wave) ----------------
#pragma unroll 1
    for (int i = 0; i < 2; ++i) {
        const int tr = wave * 2 + i;
        const int node = row0 + tr;
        if (node < B) {
            const int idxv = neigh[node * S + (lane & (S - 1))];
            const uint4 q4 = *reinterpret_cast<const uint4*>(&tile[tr][lane * 4]);
            const float4 qv = make_float4(__uint_as_float(q4.x), __uint_as_float(q4.y),
                                          __uint_as_float(q4.z), __uint_as_float(q4.w));
            float m = -INFINITY, l = 0.f;
            float4 a = make_float4(0.f, 0.f, 0.f, 0.f);
            float4 va[CH], vb[CH];
            ld_chunk(va, idxv, 0, id2feat, lane);
            ld_chunk(vb, idxv, 4, id2feat, lane);
            proc_chunk(va, qv, m, l, a);
            ld_chunk(va, idxv, 8, id2feat, lane);
            proc_chunk(vb, qv, m, l, a);
            ld_chunk(vb, idxv, 12, id2feat, lane);
            proc_chunk(va, qv, m, l, a);
            ld_chunk(va, idxv, 16, id2feat, lane);
            proc_chunk(vb, qv, m, l, a);
            ld_chunk(vb, idxv, 20, id2feat, lane);
            proc_chunk(va, qv, m, l, a);
            ld_chunk(va, idxv, 24, id2feat, lane);
            proc_chunk(vb, qv, m, l, a);
            ld_chunk(vb, idxv, 28, id2feat, lane);
            proc_chunk(va, qv, m, l, a);
            proc_chunk(vb, qv, m, l, a);
            const float inv = 1.0f / l;
            const uint4 o = make_uint4(pkbf(a.x * inv), pkbf(a.y * inv),
                                       pkbf(a.z * inv), pkbf(a.w * inv));
            *reinterpret_cast<uint4*>(&tile[tr][lane * 4]) = o;
        }
    }
    __syncthreads();

    // ---------------- phase D ----------------
#pragma unroll
    for (int n = 0; n < 4; ++n) acc[n] = (f32x4){0.f, 0.f, 0.f, 0.f};

    for (int k0 = 0; k0 < F; k0 += 32) {
        const uint4 u0 = *reinterpret_cast<const uint4*>(&tile[fr & 7][k0 + fk * 8]);
        const uint4 u1 = *reinterpret_cast<const uint4*>(&tile[fr & 7][k0 + fk * 8 + 4]);
        const short8 ah = mk8((u0.x & 0xffffu) | (u0.y << 16), (u0.z & 0xffffu) | (u0.w << 16),
                              (u1.x & 0xffffu) | (u1.y << 16), (u1.z & 0xffffu) | (u1.w << 16));
        const short8 al = mk8((u0.x >> 16) | (u0.y & 0xffff0000u), (u0.z >> 16) | (u0.w & 0xffff0000u),
                              (u1.x >> 16) | (u1.y & 0xffff0000u), (u1.z >> 16) | (u1.w & 0xffff0000u));
#pragma unroll
        for (int n = 0; n < 4; ++n) {
            const size_t boff = (size_t)((wave * 4 + n) * 16 + fr) * F + k0 + fk * 8;
            const short8 bh = *reinterpret_cast<const short8*>(&WvTh[boff]);
            const short8 bl = *reinterpret_cast<const short8*>(&WvTl[boff]);
            acc[n] = __builtin_amdgcn_mfma_f32_16x16x32_bf16(ah, bh, acc[n], 0, 0, 0);
            acc[n] = __builtin_amdgcn_mfma_f32_16x16x32_bf16(ah, bl, acc[n], 0, 0, 0);
            acc[n] = __builtin_amdgcn_mfma_f32_16x16x32_bf16(al, bh, acc[n], 0, 0, 0);
        }
    }
    if (fk < 2) {
#pragma unroll
        for (int n = 0; n < 4; ++n) {
            const int col = (wave * 4 + n) * 16 + fr;
            const float bb = bv[col];
#pragma unroll
            for (int r = 0; r < 4; ++r) {
                const int grow = row0 + fk * 4 + r;
                if (grow < B) out[(size_t)grow * E + col] = acc[n][r] + bb;
            }
        }
    }
}

// ---------------------------------------------------------------------------
extern "C" void kernel_launch(void* const* d_in, const int* in_sizes, int n_in,
                              void* d_out, int out_size, void* d_ws, size_t ws_size,
                              hipStream_t stream) {
    const int*   nodes   = (const int*)d_in[0];
    const int*   neigh   = (const int*)d_in[1];
    const float* id2feat = (const float*)d_in[2];
    const float* Wq      = (const float*)d_in[3];
    const float* bq      = (const float*)d_in[4];
    const float* Wk      = (const float*)d_in[5];
    // d_in[6] = bk unused: softmax-invariant (self column masked).
    const float* Wv      = (const float*)d_in[7];
    const float* bv      = (const float*)d_in[8];
    float* out = (float*)d_out;
    const int B = in_sizes[0];

    ushort* MTh  = (ushort*)d_ws;            // 65536 ushorts each
    ushort* MTl  = MTh + 65536;
    ushort* WvTh = MTl + 65536;
    ushort* WvTl = WvTh + 65536;
    float*  cbuf = (float*)(WvTl + 65536);   // 256 f32

    prep<<<dim3(24), dim3(512), 0, stream>>>(Wq, bq, Wk, Wv, MTh, MTl, WvTh, WvTl, cbuf);
    fused<<<dim3((B + NB - 1) / NB), dim3(256), 0, stream>>>(nodes, neigh, id2feat,
                                                             MTh, MTl, WvTh, WvTl,
                                                             cbuf, bv, out, B);
}

// Round 10
// 123.547 us; speedup vs baseline: 1.4200x; 1.4200x over previous
//
#include <hip/hip_runtime.h>
#include <math.h>

#define F 256
#define E 256
#define S 32
#define CH 4

typedef __attribute__((ext_vector_type(8))) short short8;
typedef __attribute__((ext_vector_type(4))) float f32x4;

__device__ __forceinline__ ushort f2bf(float x) {
    uint u = __float_as_uint(x);
    return (ushort)((u + 0x7fffu + ((u >> 16) & 1u)) >> 16);
}
__device__ __forceinline__ float bf2f(ushort h) {
    return __uint_as_float(((uint)h) << 16);
}
__device__ __forceinline__ uint4 pack8(const ushort* h) {
    uint4 r;
    r.x = (uint)h[0] | ((uint)h[1] << 16); r.y = (uint)h[2] | ((uint)h[3] << 16);
    r.z = (uint)h[4] | ((uint)h[5] << 16); r.w = (uint)h[6] | ((uint)h[7] << 16);
    return r;
}
__device__ __forceinline__ void split4(const float* x, uint2& ph, uint2& pl) {
    ushort h[4], l[4];
#pragma unroll
    for (int i = 0; i < 4; ++i) { h[i] = f2bf(x[i]); l[i] = f2bf(x[i] - bf2f(h[i])); }
    ph.x = (uint)h[0] | ((uint)h[1] << 16); ph.y = (uint)h[2] | ((uint)h[3] << 16);
    pl.x = (uint)l[0] | ((uint)l[1] << 16); pl.y = (uint)l[2] | ((uint)l[3] << 16);
}
__device__ __forceinline__ void split8(const float* x, short8& h, short8& l) {
    ushort hh[8], ll[8];
#pragma unroll
    for (int i = 0; i < 8; ++i) { hh[i] = f2bf(x[i]); ll[i] = f2bf(x[i] - bf2f(hh[i])); }
    uint4 ph = pack8(hh), pl = pack8(ll);
    h = *reinterpret_cast<short8*>(&ph);
    l = *reinterpret_cast<short8*>(&pl);
}
__device__ __forceinline__ short8 mk8(uint a, uint b, uint c, uint d) {
    uint4 p = make_uint4(a, b, c, d);
    return *reinterpret_cast<short8*>(&p);
}
__device__ __forceinline__ uint pkbf(float v) {
    const ushort h = f2bf(v);
    const ushort l = f2bf(v - bf2f(h));
    return (uint)h | ((uint)l << 16);
}

// ---------------------------------------------------------------------------
// prep (proven, R8): blocks 0..3 -> MT[j][i] = Wk_j . Wq_i (bf16x3 MFMA from
// global), split hi/lo; blocks 4..19 -> WvT transpose/split; 20..23 -> c.
// ---------------------------------------------------------------------------
__global__ __launch_bounds__(512) void prep(const float* __restrict__ Wq,
                                            const float* __restrict__ bq,
                                            const float* __restrict__ Wk,
                                            const float* __restrict__ Wv,
                                            ushort* __restrict__ MTh,
                                            ushort* __restrict__ MTl,
                                            ushort* __restrict__ WvTh,
                                            ushort* __restrict__ WvTl,
                                            float* __restrict__ c) {
    const int blk = blockIdx.x, tid = threadIdx.x;
    const int lane = tid & 63, wave = tid >> 6;
    if (blk < 4) {
        const int wm = wave >> 2, wn = wave & 3;
        const int fr = lane & 15, fk = lane >> 4;
        const int j0 = blk * 64;
        f32x4 acc[2][4];
#pragma unroll
        for (int m = 0; m < 2; ++m)
#pragma unroll
            for (int n = 0; n < 4; ++n) acc[m][n] = (f32x4){0.f, 0.f, 0.f, 0.f};
        for (int k0 = 0; k0 < F; k0 += 32) {
            short8 ah[2], al[2];
#pragma unroll
            for (int m = 0; m < 2; ++m) {
                const float* p = &Wk[(size_t)(j0 + wm * 32 + m * 16 + fr) * F + k0 + fk * 8];
                float x[8];
                *reinterpret_cast<float4*>(&x[0]) = *reinterpret_cast<const float4*>(p);
                *reinterpret_cast<float4*>(&x[4]) = *reinterpret_cast<const float4*>(p + 4);
                split8(x, ah[m], al[m]);
            }
#pragma unroll
            for (int n = 0; n < 4; ++n) {
                const float* p = &Wq[(size_t)(wn * 64 + n * 16 + fr) * F + k0 + fk * 8];
                float x[8];
                *reinterpret_cast<float4*>(&x[0]) = *reinterpret_cast<const float4*>(p);
                *reinterpret_cast<float4*>(&x[4]) = *reinterpret_cast<const float4*>(p + 4);
                short8 bh, bl;
                split8(x, bh, bl);
#pragma unroll
                for (int m = 0; m < 2; ++m) {
                    acc[m][n] = __builtin_amdgcn_mfma_f32_16x16x32_bf16(ah[m], bh, acc[m][n], 0, 0, 0);
                    acc[m][n] = __builtin_amdgcn_mfma_f32_16x16x32_bf16(ah[m], bl, acc[m][n], 0, 0, 0);
                    acc[m][n] = __builtin_amdgcn_mfma_f32_16x16x32_bf16(al[m], bh, acc[m][n], 0, 0, 0);
                }
            }
        }
#pragma unroll
        for (int n = 0; n < 4; ++n) {
            const int i = wn * 64 + n * 16 + fr;
#pragma unroll
            for (int m = 0; m < 2; ++m)
#pragma unroll
                for (int r = 0; r < 4; ++r) {
                    const int j = j0 + wm * 32 + m * 16 + fk * 4 + r;
                    const float v = acc[m][n][r];
                    const ushort h = f2bf(v);
                    MTh[(size_t)j * F + i] = h;
                    MTl[(size_t)j * F + i] = f2bf(v - bf2f(h));
                }
        }
    } else if (blk < 20) {
        __shared__ float t[64][65];
        const int tb = blk - 4;
        const int jt = (tb & 3) * 64, kt = (tb >> 2) * 64;
        const int lk = tid >> 3, lj = (tid & 7) * 8;
        {
            const float* p = &Wv[(size_t)(kt + lk) * E + jt + lj];
            const float4 v0 = *reinterpret_cast<const float4*>(p);
            const float4 v1 = *reinterpret_cast<const float4*>(p + 4);
            t[lk][lj + 0] = v0.x; t[lk][lj + 1] = v0.y; t[lk][lj + 2] = v0.z; t[lk][lj + 3] = v0.w;
            t[lk][lj + 4] = v1.x; t[lk][lj + 5] = v1.y; t[lk][lj + 6] = v1.z; t[lk][lj + 7] = v1.w;
        }
        __syncthreads();
        const int oj = tid >> 3, ok = (tid & 7) * 8;
        ushort h[8], l[8];
#pragma unroll
        for (int u = 0; u < 8; ++u) {
            const float v = t[ok + u][oj];
            h[u] = f2bf(v); l[u] = f2bf(v - bf2f(h[u]));
        }
        *reinterpret_cast<uint4*>(&WvTh[(size_t)(jt + oj) * F + kt + ok]) = pack8(h);
        *reinterpret_cast<uint4*>(&WvTl[(size_t)(jt + oj) * F + kt + ok]) = pack8(l);
    } else {
        __shared__ float bqs[F];
        if (tid < F) bqs[tid] = bq[tid];
        __syncthreads();
        const float4 b4 = *reinterpret_cast<const float4*>(&bqs[lane * 4]);
#pragma unroll
        for (int i = 0; i < 8; ++i) {
            const int j = (blk - 20) * 64 + wave * 8 + i;
            const float4 k4 = *reinterpret_cast<const float4*>(&Wk[(size_t)j * F + lane * 4]);
            float p = k4.x * b4.x + k4.y * b4.y + k4.z * b4.z + k4.w * b4.w;
#pragma unroll
            for (int off = 32; off; off >>= 1) p += __shfl_xor(p, off);
            if (lane == 0) c[j] = p;
        }
    }
}

// ---------------------------------------------------------------------------
// qgemm: q~ = gather(id2feat,nodes) @ MT + c, f32 out.
// BM=32, BN=128, BK=32, 256 thr = 4 waves (each wave 32x32 = 2Mx2N frags).
// Grid (313, 2) = 626 blocks (~2.4/CU). A double-buffered in LDS, ONE barrier
// per k-iter; B fragments straight from L2-hot split tables.
// ---------------------------------------------------------------------------
__global__ __launch_bounds__(256) void qgemm(const float* __restrict__ X,
                                             const int* __restrict__ nodes,
                                             const ushort* __restrict__ BTh,
                                             const ushort* __restrict__ BTl,
                                             const float* __restrict__ cb,
                                             float* __restrict__ outq,
                                             int B) {
    __shared__ ushort Ah[2][32][40], Al[2][32][40];
    const int tid = threadIdx.x, lane = tid & 63, wave = tid >> 6;
    const int fr = lane & 15, fk = lane >> 4;
    const int row0 = blockIdx.x * 32;
    const int col0 = blockIdx.y * 128 + wave * 32;

    // A staging: thread -> row tid>>3, k-quad (tid&7)*4
    const int arL = tid >> 3, akL = (tid & 7) * 4;
    const int gr = row0 + arL;
    const int grc = gr < B ? gr : B - 1;
    const float* aptr = X + (size_t)nodes[grc] * F + akL;

    f32x4 acc[2][2];
#pragma unroll
    for (int m = 0; m < 2; ++m)
#pragma unroll
        for (int n = 0; n < 2; ++n) acc[m][n] = (f32x4){0.f, 0.f, 0.f, 0.f};

    {   // prologue: stage k-tile 0
        const float4 av = *reinterpret_cast<const float4*>(aptr);
        uint2 h, l; split4(&av.x, h, l);
        *reinterpret_cast<uint2*>(&Ah[0][arL][akL]) = h;
        *reinterpret_cast<uint2*>(&Al[0][arL][akL]) = l;
    }
    __syncthreads();

    for (int t = 0; t < 8; ++t) {
        const int cur = t & 1;
        float4 nv;
        if (t < 7) nv = *reinterpret_cast<const float4*>(aptr + (t + 1) * 32);

        short8 a_h[2], a_l[2];
#pragma unroll
        for (int m = 0; m < 2; ++m) {
            a_h[m] = *reinterpret_cast<const short8*>(&Ah[cur][m * 16 + fr][fk * 8]);
            a_l[m] = *reinterpret_cast<const short8*>(&Al[cur][m * 16 + fr][fk * 8]);
        }
#pragma unroll
        for (int n = 0; n < 2; ++n) {
            const size_t boff = (size_t)(col0 + n * 16 + fr) * F + t * 32 + fk * 8;
            const short8 bh = *reinterpret_cast<const short8*>(&BTh[boff]);
            const short8 bl = *reinterpret_cast<const short8*>(&BTl[boff]);
#pragma unroll
            for (int m = 0; m < 2; ++m) {
                acc[m][n] = __builtin_amdgcn_mfma_f32_16x16x32_bf16(a_h[m], bh, acc[m][n], 0, 0, 0);
                acc[m][n] = __builtin_amdgcn_mfma_f32_16x16x32_bf16(a_h[m], bl, acc[m][n], 0, 0, 0);
                acc[m][n] = __builtin_amdgcn_mfma_f32_16x16x32_bf16(a_l[m], bh, acc[m][n], 0, 0, 0);
            }
        }
        if (t < 7) {   // stage next tile into the other buffer (read this iter: cur)
            uint2 h, l; split4(&nv.x, h, l);
            *reinterpret_cast<uint2*>(&Ah[cur ^ 1][arL][akL]) = h;
            *reinterpret_cast<uint2*>(&Al[cur ^ 1][arL][akL]) = l;
        }
        __syncthreads();
    }

    // epilogue: C/D map col=fr-part, row=fk*4+reg
#pragma unroll
    for (int n = 0; n < 2; ++n) {
        const int col = col0 + n * 16 + fr;
        const float cc = cb[col];
#pragma unroll
        for (int m = 0; m < 2; ++m)
#pragma unroll
            for (int r = 0; r < 4; ++r) {
                const int row = row0 + m * 16 + fk * 4 + r;
                if (row < B) outq[(size_t)row * F + col] = acc[m][n][r] + cc;
            }
    }
}

// ---------------------------------------------------------------------------
// attn helpers (proven online-softmax gather, R3)
// ---------------------------------------------------------------------------
__device__ __forceinline__ void ld_chunk(float4* d, int idxv, int s0,
                                         const float* __restrict__ t, int lane) {
#pragma unroll
    for (int j = 0; j < CH; ++j) {
        const int nid = __builtin_amdgcn_readlane(idxv, s0 + j);
        d[j] = *reinterpret_cast<const float4*>(&t[(size_t)nid * F + lane * 4]);
    }
}
__device__ __forceinline__ void proc_chunk(const float4* v, const float4 qv,
                                           float& m, float& l, float4& acc) {
#pragma unroll
    for (int j = 0; j < CH; ++j) {
        float p = v[j].x * qv.x + v[j].y * qv.y + v[j].z * qv.z + v[j].w * qv.w;
#pragma unroll
        for (int off = 32; off; off >>= 1) p += __shfl_xor(p, off);
        if (p <= m) {
            const float w = __expf(p - m);
            l += w;
            acc.x += w * v[j].x; acc.y += w * v[j].y;
            acc.z += w * v[j].z; acc.w += w * v[j].w;
        } else {
            const float cc = __expf(m - p);
            l = l * cc + 1.f;
            acc.x = acc.x * cc + v[j].x; acc.y = acc.y * cc + v[j].y;
            acc.z = acc.z * cc + v[j].z; acc.w = acc.w * cc + v[j].w;
            m = p;
        }
    }
}

// ---------------------------------------------------------------------------
// gatherD: the PROVEN standalone gather config (2500 blocks x 4 waves, one
// node per wave, online softmax) + a cheap MFMA D-tail: m -> 4KB LDS packed
// bf16 hi|lo, one barrier, out[4][256] = m @ WvT_hi + bv. Only the back-end
// GEMM is fused (its table reads land in the gather's HBM-stall slack);
// the front GEMM stays a separate dispatch (R6-R9 showed front-fusion
// serializes table streaming at block start).
// ---------------------------------------------------------------------------
__global__ __launch_bounds__(256) void gatherD(const int* __restrict__ neigh,
                                               const float* __restrict__ id2feat,
                                               const float* __restrict__ qtm,
                                               const ushort* __restrict__ WvTh,
                                               const float* __restrict__ bv,
                                               float* __restrict__ out,
                                               int B) {
    __shared__ uint tile[4][260];
    const int tid = threadIdx.x, lane = tid & 63, wave = tid >> 6;
    const int node = blockIdx.x * 4 + wave;

    if (node < B) {
        const int idxv = neigh[node * S + (lane & (S - 1))];
        const float4 qv = *reinterpret_cast<const float4*>(&qtm[(size_t)node * F + lane * 4]);
        float m = -INFINITY, l = 0.f;
        float4 a = make_float4(0.f, 0.f, 0.f, 0.f);
        float4 va[CH], vb[CH];
        ld_chunk(va, idxv, 0, id2feat, lane);
        ld_chunk(vb, idxv, 4, id2feat, lane);
        proc_chunk(va, qv, m, l, a);
        ld_chunk(va, idxv, 8, id2feat, lane);
        proc_chunk(vb, qv, m, l, a);
        ld_chunk(vb, idxv, 12, id2feat, lane);
        proc_chunk(va, qv, m, l, a);
        ld_chunk(va, idxv, 16, id2feat, lane);
        proc_chunk(vb, qv, m, l, a);
        ld_chunk(vb, idxv, 20, id2feat, lane);
        proc_chunk(va, qv, m, l, a);
        ld_chunk(va, idxv, 24, id2feat, lane);
        proc_chunk(vb, qv, m, l, a);
        ld_chunk(vb, idxv, 28, id2feat, lane);
        proc_chunk(va, qv, m, l, a);
        proc_chunk(vb, qv, m, l, a);
        const float inv = 1.0f / l;
        const uint4 o = make_uint4(pkbf(a.x * inv), pkbf(a.y * inv),
                                   pkbf(a.z * inv), pkbf(a.w * inv));
        *reinterpret_cast<uint4*>(&tile[wave][lane * 4]) = o;
    }
    __syncthreads();

    // D phase: out rows = this block's 4 nodes. A row fr -> tile[fr&3]
    // (rows 4..15 duplicates, their C rows discarded; C row = fk*4+r, only
    // fk==0 rows 0..3 are real). (mh+ml)*Wh: hi-only WvT, err ~2e-3.
    const int fr = lane & 15, fk = lane >> 4;
    f32x4 acc[4];
#pragma unroll
    for (int n = 0; n < 4; ++n) acc[n] = (f32x4){0.f, 0.f, 0.f, 0.f};

    for (int k0 = 0; k0 < F; k0 += 32) {
        const uint4 u0 = *reinterpret_cast<const uint4*>(&tile[fr & 3][k0 + fk * 8]);
        const uint4 u1 = *reinterpret_cast<const uint4*>(&tile[fr & 3][k0 + fk * 8 + 4]);
        const short8 ah = mk8((u0.x & 0xffffu) | (u0.y << 16), (u0.z & 0xffffu) | (u0.w << 16),
                              (u1.x & 0xffffu) | (u1.y << 16), (u1.z & 0xffffu) | (u1.w << 16));
        const short8 al = mk8((u0.x >> 16) | (u0.y & 0xffff0000u), (u0.z >> 16) | (u0.w & 0xffff0000u),
                              (u1.x >> 16) | (u1.y & 0xffff0000u), (u1.z >> 16) | (u1.w & 0xffff0000u));
#pragma unroll
        for (int n = 0; n < 4; ++n) {
            const size_t boff = (size_t)(wave * 64 + n * 16 + fr) * F + k0 + fk * 8;
            const short8 bh = *reinterpret_cast<const short8*>(&WvTh[boff]);
            acc[n] = __builtin_amdgcn_mfma_f32_16x16x32_bf16(ah, bh, acc[n], 0, 0, 0);
            acc[n] = __builtin_amdgcn_mfma_f32_16x16x32_bf16(al, bh, acc[n], 0, 0, 0);
        }
    }
    if (fk == 0) {
#pragma unroll
        for (int n = 0; n < 4; ++n) {
            const int col = wave * 64 + n * 16 + fr;
            const float bb = bv[col];
#pragma unroll
            for (int r = 0; r < 4; ++r) {
                const int grow = blockIdx.x * 4 + r;
                if (grow < B) out[(size_t)grow * E + col] = acc[n][r] + bb;
            }
        }
    }
}

// ---------------------------------------------------------------------------
extern "C" void kernel_launch(void* const* d_in, const int* in_sizes, int n_in,
                              void* d_out, int out_size, void* d_ws, size_t ws_size,
                              hipStream_t stream) {
    const int*   nodes   = (const int*)d_in[0];
    const int*   neigh   = (const int*)d_in[1];
    const float* id2feat = (const float*)d_in[2];
    const float* Wq      = (const float*)d_in[3];
    const float* bq      = (const float*)d_in[4];
    const float* Wk      = (const float*)d_in[5];
    // d_in[6] = bk unused: softmax-invariant (self column masked).
    const float* Wv      = (const float*)d_in[7];
    const float* bv      = (const float*)d_in[8];
    float* out = (float*)d_out;
    const int B = in_sizes[0];

    ushort* MTh  = (ushort*)d_ws;            // 65536 ushorts each
    ushort* MTl  = MTh + 65536;
    ushort* WvTh = MTl + 65536;
    ushort* WvTl = WvTh + 65536;
    float*  cbuf = (float*)(WvTl + 65536);   // 256 f32
    float*  qtm  = cbuf + 256;               // [B][F] f32 q~

    prep<<<dim3(24), dim3(512), 0, stream>>>(Wq, bq, Wk, Wv, MTh, MTl, WvTh, WvTl, cbuf);
    qgemm<<<dim3((B + 31) / 32, 2), dim3(256), 0, stream>>>(id2feat, nodes,
                                                            MTh, MTl, cbuf, qtm, B);
    gatherD<<<dim3((B + 3) / 4), dim3(256), 0, stream>>>(neigh, id2feat, qtm,
                                                         WvTh, bv, out, B);
}

// Round 11
// 121.793 us; speedup vs baseline: 1.4404x; 1.0144x over previous
//
#include <hip/hip_runtime.h>
#include <math.h>

#define F 256
#define E 256
#define S 32
#define CH 4

typedef __attribute__((ext_vector_type(8))) short short8;
typedef __attribute__((ext_vector_type(4))) float f32x4;

__device__ __forceinline__ ushort f2bf(float x) {
    uint u = __float_as_uint(x);
    return (ushort)((u + 0x7fffu + ((u >> 16) & 1u)) >> 16);
}
__device__ __forceinline__ float bf2f(ushort h) {
    return __uint_as_float(((uint)h) << 16);
}
__device__ __forceinline__ uint4 pack8(const ushort* h) {
    uint4 r;
    r.x = (uint)h[0] | ((uint)h[1] << 16); r.y = (uint)h[2] | ((uint)h[3] << 16);
    r.z = (uint)h[4] | ((uint)h[5] << 16); r.w = (uint)h[6] | ((uint)h[7] << 16);
    return r;
}
__device__ __forceinline__ void split4(const float* x, uint2& ph, uint2& pl) {
    ushort h[4], l[4];
#pragma unroll
    for (int i = 0; i < 4; ++i) { h[i] = f2bf(x[i]); l[i] = f2bf(x[i] - bf2f(h[i])); }
    ph.x = (uint)h[0] | ((uint)h[1] << 16); ph.y = (uint)h[2] | ((uint)h[3] << 16);
    pl.x = (uint)l[0] | ((uint)l[1] << 16); pl.y = (uint)l[2] | ((uint)l[3] << 16);
}
__device__ __forceinline__ void split8(const float* x, short8& h, short8& l) {
    ushort hh[8], ll[8];
#pragma unroll
    for (int i = 0; i < 8; ++i) { hh[i] = f2bf(x[i]); ll[i] = f2bf(x[i] - bf2f(hh[i])); }
    uint4 ph = pack8(hh), pl = pack8(ll);
    h = *reinterpret_cast<short8*>(&ph);
    l = *reinterpret_cast<short8*>(&pl);
}

// ---------------------------------------------------------------------------
// prep (proven): blocks 0..3 -> MT[j][i] = Wk_j . Wq_i (bf16x3 MFMA from
// global), split hi/lo; blocks 4..19 -> WvT transpose/split; 20..23 -> c.
// ---------------------------------------------------------------------------
__global__ __launch_bounds__(512) void prep(const float* __restrict__ Wq,
                                            const float* __restrict__ bq,
                                            const float* __restrict__ Wk,
                                            const float* __restrict__ Wv,
                                            ushort* __restrict__ MTh,
                                            ushort* __restrict__ MTl,
                                            ushort* __restrict__ WvTh,
                                            ushort* __restrict__ WvTl,
                                            float* __restrict__ c) {
    const int blk = blockIdx.x, tid = threadIdx.x;
    const int lane = tid & 63, wave = tid >> 6;
    if (blk < 4) {
        const int wm = wave >> 2, wn = wave & 3;
        const int fr = lane & 15, fk = lane >> 4;
        const int j0 = blk * 64;
        f32x4 acc[2][4];
#pragma unroll
        for (int m = 0; m < 2; ++m)
#pragma unroll
            for (int n = 0; n < 4; ++n) acc[m][n] = (f32x4){0.f, 0.f, 0.f, 0.f};
        for (int k0 = 0; k0 < F; k0 += 32) {
            short8 ah[2], al[2];
#pragma unroll
            for (int m = 0; m < 2; ++m) {
                const float* p = &Wk[(size_t)(j0 + wm * 32 + m * 16 + fr) * F + k0 + fk * 8];
                float x[8];
                *reinterpret_cast<float4*>(&x[0]) = *reinterpret_cast<const float4*>(p);
                *reinterpret_cast<float4*>(&x[4]) = *reinterpret_cast<const float4*>(p + 4);
                split8(x, ah[m], al[m]);
            }
#pragma unroll
            for (int n = 0; n < 4; ++n) {
                const float* p = &Wq[(size_t)(wn * 64 + n * 16 + fr) * F + k0 + fk * 8];
                float x[8];
                *reinterpret_cast<float4*>(&x[0]) = *reinterpret_cast<const float4*>(p);
                *reinterpret_cast<float4*>(&x[4]) = *reinterpret_cast<const float4*>(p + 4);
                short8 bh, bl;
                split8(x, bh, bl);
#pragma unroll
                for (int m = 0; m < 2; ++m) {
                    acc[m][n] = __builtin_amdgcn_mfma_f32_16x16x32_bf16(ah[m], bh, acc[m][n], 0, 0, 0);
                    acc[m][n] = __builtin_amdgcn_mfma_f32_16x16x32_bf16(ah[m], bl, acc[m][n], 0, 0, 0);
                    acc[m][n] = __builtin_amdgcn_mfma_f32_16x16x32_bf16(al[m], bh, acc[m][n], 0, 0, 0);
                }
            }
        }
#pragma unroll
        for (int n = 0; n < 4; ++n) {
            const int i = wn * 64 + n * 16 + fr;
#pragma unroll
            for (int m = 0; m < 2; ++m)
#pragma unroll
                for (int r = 0; r < 4; ++r) {
                    const int j = j0 + wm * 32 + m * 16 + fk * 4 + r;
                    const float v = acc[m][n][r];
                    const ushort h = f2bf(v);
                    MTh[(size_t)j * F + i] = h;
                    MTl[(size_t)j * F + i] = f2bf(v - bf2f(h));
                }
        }
    } else if (blk < 20) {
        __shared__ float t[64][65];
        const int tb = blk - 4;
        const int jt = (tb & 3) * 64, kt = (tb >> 2) * 64;
        const int lk = tid >> 3, lj = (tid & 7) * 8;
        {
            const float* p = &Wv[(size_t)(kt + lk) * E + jt + lj];
            const float4 v0 = *reinterpret_cast<const float4*>(p);
            const float4 v1 = *reinterpret_cast<const float4*>(p + 4);
            t[lk][lj + 0] = v0.x; t[lk][lj + 1] = v0.y; t[lk][lj + 2] = v0.z; t[lk][lj + 3] = v0.w;
            t[lk][lj + 4] = v1.x; t[lk][lj + 5] = v1.y; t[lk][lj + 6] = v1.z; t[lk][lj + 7] = v1.w;
        }
        __syncthreads();
        const int oj = tid >> 3, ok = (tid & 7) * 8;
        ushort h[8], l[8];
#pragma unroll
        for (int u = 0; u < 8; ++u) {
            const float v = t[ok + u][oj];
            h[u] = f2bf(v); l[u] = f2bf(v - bf2f(h[u]));
        }
        *reinterpret_cast<uint4*>(&WvTh[(size_t)(jt + oj) * F + kt + ok]) = pack8(h);
        *reinterpret_cast<uint4*>(&WvTl[(size_t)(jt + oj) * F + kt + ok]) = pack8(l);
    } else {
        __shared__ float bqs[F];
        if (tid < F) bqs[tid] = bq[tid];
        __syncthreads();
        const float4 b4 = *reinterpret_cast<const float4*>(&bqs[lane * 4]);
#pragma unroll
        for (int i = 0; i < 8; ++i) {
            const int j = (blk - 20) * 64 + wave * 8 + i;
            const float4 k4 = *reinterpret_cast<const float4*>(&Wk[(size_t)j * F + lane * 4]);
            float p = k4.x * b4.x + k4.y * b4.y + k4.z * b4.z + k4.w * b4.w;
#pragma unroll
            for (int off = 32; off; off >>= 1) p += __shfl_xor(p, off);
            if (lane == 0) c[j] = p;
        }
    }
}

// ---------------------------------------------------------------------------
// gemm32: out[r][:] = X[idx?idx[r]:r][:] @ BT(hi/lo) + bias, f32 out.
// BM=32, BN=128, BK=32, 256 thr = 4 waves. Grid (ceil(rows/32), 2).
// A double-buffered in LDS (one barrier/iter); B fragments straight from the
// L2-hot split tables (64B/row contiguous per fragment read).
// ---------------------------------------------------------------------------
__global__ __launch_bounds__(256) void gemm32(const float* __restrict__ X,
                                              const int* __restrict__ idx,
                                              const ushort* __restrict__ BTh,
                                              const ushort* __restrict__ BTl,
                                              const float* __restrict__ bias,
                                              float* __restrict__ outp,
                                              int rows) {
    __shared__ ushort Ah[2][32][40], Al[2][32][40];
    const int tid = threadIdx.x, lane = tid & 63, wave = tid >> 6;
    const int fr = lane & 15, fk = lane >> 4;
    const int row0 = blockIdx.x * 32;
    const int col0 = blockIdx.y * 128 + wave * 32;

    const int arL = tid >> 3, akL = (tid & 7) * 4;
    const int gr = row0 + arL;
    const int grc = gr < rows ? gr : rows - 1;
    const long arow = idx ? (long)idx[grc] : (long)grc;
    const float* aptr = X + arow * (long)F + akL;

    f32x4 acc[2][2];
#pragma unroll
    for (int m = 0; m < 2; ++m)
#pragma unroll
        for (int n = 0; n < 2; ++n) acc[m][n] = (f32x4){0.f, 0.f, 0.f, 0.f};

    {
        const float4 av = *reinterpret_cast<const float4*>(aptr);
        uint2 h, l; split4(&av.x, h, l);
        *reinterpret_cast<uint2*>(&Ah[0][arL][akL]) = h;
        *reinterpret_cast<uint2*>(&Al[0][arL][akL]) = l;
    }
    __syncthreads();

    for (int t = 0; t < 8; ++t) {
        const int cur = t & 1;
        float4 nv;
        if (t < 7) nv = *reinterpret_cast<const float4*>(aptr + (t + 1) * 32);

        short8 a_h[2], a_l[2];
#pragma unroll
        for (int m = 0; m < 2; ++m) {
            a_h[m] = *reinterpret_cast<const short8*>(&Ah[cur][m * 16 + fr][fk * 8]);
            a_l[m] = *reinterpret_cast<const short8*>(&Al[cur][m * 16 + fr][fk * 8]);
        }
#pragma unroll
        for (int n = 0; n < 2; ++n) {
            const size_t boff = (size_t)(col0 + n * 16 + fr) * F + t * 32 + fk * 8;
            const short8 bh = *reinterpret_cast<const short8*>(&BTh[boff]);
            const short8 bl = *reinterpret_cast<const short8*>(&BTl[boff]);
#pragma unroll
            for (int m = 0; m < 2; ++m) {
                acc[m][n] = __builtin_amdgcn_mfma_f32_16x16x32_bf16(a_h[m], bh, acc[m][n], 0, 0, 0);
                acc[m][n] = __builtin_amdgcn_mfma_f32_16x16x32_bf16(a_h[m], bl, acc[m][n], 0, 0, 0);
                acc[m][n] = __builtin_amdgcn_mfma_f32_16x16x32_bf16(a_l[m], bh, acc[m][n], 0, 0, 0);
            }
        }
        if (t < 7) {
            uint2 h, l; split4(&nv.x, h, l);
            *reinterpret_cast<uint2*>(&Ah[cur ^ 1][arL][akL]) = h;
            *reinterpret_cast<uint2*>(&Al[cur ^ 1][arL][akL]) = l;
        }
        __syncthreads();
    }

#pragma unroll
    for (int n = 0; n < 2; ++n) {
        const int col = col0 + n * 16 + fr;
        const float cc = bias[col];
#pragma unroll
        for (int m = 0; m < 2; ++m)
#pragma unroll
            for (int r = 0; r < 4; ++r) {
                const int row = row0 + m * 16 + fk * 4 + r;
                if (row < rows) outp[(size_t)row * F + col] = acc[m][n][r] + cc;
            }
    }
}

// ---------------------------------------------------------------------------
// attn_gather (PROVEN 60.5 us config, R3): one wave per node, single-pass
// online softmax, 4-row double-buffered chunks, m written back to qtm.
// ---------------------------------------------------------------------------
__device__ __forceinline__ void ld_chunk(float4* d, int idxv, int s0,
                                         const float* __restrict__ t, int lane) {
#pragma unroll
    for (int j = 0; j < CH; ++j) {
        const int nid = __builtin_amdgcn_readlane(idxv, s0 + j);
        d[j] = *reinterpret_cast<const float4*>(&t[(size_t)nid * F + lane * 4]);
    }
}
__device__ __forceinline__ void proc_chunk(const float4* v, const float4 qv,
                                           float& m, float& l, float4& acc) {
#pragma unroll
    for (int j = 0; j < CH; ++j) {
        float p = v[j].x * qv.x + v[j].y * qv.y + v[j].z * qv.z + v[j].w * qv.w;
#pragma unroll
        for (int off = 32; off; off >>= 1) p += __shfl_xor(p, off);
        if (p <= m) {
            const float w = __expf(p - m);
            l += w;
            acc.x += w * v[j].x; acc.y += w * v[j].y;
            acc.z += w * v[j].z; acc.w += w * v[j].w;
        } else {
            const float cc = __expf(m - p);
            l = l * cc + 1.f;
            acc.x = acc.x * cc + v[j].x; acc.y = acc.y * cc + v[j].y;
            acc.z = acc.z * cc + v[j].z; acc.w = acc.w * cc + v[j].w;
            m = p;
        }
    }
}

__global__ __launch_bounds__(256) void attn_gather(const int* __restrict__ neigh_idx,
                                                   const float* __restrict__ id2feat,
                                                   float* __restrict__ qtm,
                                                   int B) {
    const int node = blockIdx.x * 4 + (threadIdx.x >> 6);
    const int lane = threadIdx.x & 63;
    if (node >= B) return;

    const int idxv = neigh_idx[node * S + (lane & (S - 1))];
    const float4 qv = *reinterpret_cast<const float4*>(&qtm[(size_t)node * F + lane * 4]);

    float m = -INFINITY, l = 0.f;
    float4 acc = make_float4(0.f, 0.f, 0.f, 0.f);

    float4 va[CH], vb[CH];
    ld_chunk(va, idxv, 0, id2feat, lane);
    ld_chunk(vb, idxv, 4, id2feat, lane);
    proc_chunk(va, qv, m, l, acc);
    ld_chunk(va, idxv, 8, id2feat, lane);
    proc_chunk(vb, qv, m, l, acc);
    ld_chunk(vb, idxv, 12, id2feat, lane);
    proc_chunk(va, qv, m, l, acc);
    ld_chunk(va, idxv, 16, id2feat, lane);
    proc_chunk(vb, qv, m, l, acc);
    ld_chunk(vb, idxv, 20, id2feat, lane);
    proc_chunk(va, qv, m, l, acc);
    ld_chunk(va, idxv, 24, id2feat, lane);
    proc_chunk(vb, qv, m, l, acc);
    ld_chunk(vb, idxv, 28, id2feat, lane);
    proc_chunk(va, qv, m, l, acc);
    proc_chunk(vb, qv, m, l, acc);

    const float inv = 1.0f / l;
    float4 o;
    o.x = acc.x * inv; o.y = acc.y * inv; o.z = acc.z * inv; o.w = acc.w * inv;
    *reinterpret_cast<float4*>(&qtm[(size_t)node * F + lane * 4]) = o;
}

// ---------------------------------------------------------------------------
extern "C" void kernel_launch(void* const* d_in, const int* in_sizes, int n_in,
                              void* d_out, int out_size, void* d_ws, size_t ws_size,
                              hipStream_t stream) {
    const int*   nodes   = (const int*)d_in[0];
    const int*   neigh   = (const int*)d_in[1];
    const float* id2feat = (const float*)d_in[2];
    const float* Wq      = (const float*)d_in[3];
    const float* bq      = (const float*)d_in[4];
    const float* Wk      = (const float*)d_in[5];
    // d_in[6] = bk unused: softmax-invariant (self column masked).
    const float* Wv      = (const float*)d_in[7];
    const float* bv      = (const float*)d_in[8];
    float* out = (float*)d_out;
    const int B = in_sizes[0];

    ushort* MTh  = (ushort*)d_ws;            // 65536 ushorts each
    ushort* MTl  = MTh + 65536;
    ushort* WvTh = MTl + 65536;
    ushort* WvTl = WvTh + 65536;
    float*  cbuf = (float*)(WvTl + 65536);   // 256 f32
    float*  qtm  = cbuf + 256;               // [B][F] f32: q~, then m (in place)

    // 1) tables
    prep<<<dim3(24), dim3(512), 0, stream>>>(Wq, bq, Wk, Wv, MTh, MTl, WvTh, WvTl, cbuf);
    // 2) q~ = gather(id2feat, nodes) @ MT + c
    gemm32<<<dim3((B + 31) / 32, 2), dim3(256), 0, stream>>>(id2feat, nodes,
                                                             MTh, MTl, cbuf, qtm, B);
    // 3) scores -> softmax -> m (in place over qtm), proven standalone config
    attn_gather<<<dim3((B + 3) / 4), dim3(256), 0, stream>>>(neigh, id2feat, qtm, B);
    // 4) out = m @ WvT + bv (full hi/lo accuracy)
    gemm32<<<dim3((B + 31) / 32, 2), dim3(256), 0, stream>>>(qtm, nullptr,
                                                             WvTh, WvTl, bv, out, B);
}